// Round 10
// baseline (51.647 us; speedup 1.0000x reference)
//
#include <hip/hip_runtime.h>
#include <hip/hip_bf16.h>

// Problem constants (fixed by reference):
#define SS 512
#define HH 768
#define LL 32
#define DD 1536   // 2*H
#define MM 2048   // B*L rows
#define KK DD     // GEMM K
#define NMS 12    // macro K-steps (each stages 128 cols; each K-group eats 64)

typedef float f32x4 __attribute__((ext_vector_type(4)));
typedef short bf16x8 __attribute__((ext_vector_type(8)));

__device__ __forceinline__ unsigned short f2bf(float x) {
    union { float f; unsigned u; } v; v.f = x;
    unsigned r = v.u + 0x7fff + ((v.u >> 16) & 1);   // round-to-nearest-even
    return (unsigned short)(r >> 16);
}

__device__ __forceinline__ void gload16(const unsigned short* g, unsigned short* l) {
    // async global->LDS, 16B/lane; LDS dest = wave-uniform base + lane*16
    __builtin_amdgcn_global_load_lds(
        (const __attribute__((address_space(1))) void*)g,
        (__attribute__((address_space(3))) void*)l, 16, 0, 0);
}

// ---------------------------------------------------------------------------
// Fused prep, 192 threads/block (float4 per thread):
//   blocks [0,2048)    : clause_h rows (bf16)  [mean(768) | cls(768)]
//   blocks [2048,5120) : W_pool f32->bf16
//   blocks [5120,5131) : init logits to b_out
// (unchanged from R7 — measured at its HBM floor ~19 us)
// ---------------------------------------------------------------------------
__global__ __launch_bounds__(192)
void prep(const float* __restrict__ seq, const int* __restrict__ pos,
          const float* __restrict__ Wp, const float* __restrict__ bo,
          unsigned short* __restrict__ Abf, unsigned short* __restrict__ Wbf,
          float* __restrict__ out) {
    const int blk = blockIdx.x;
    const int tid = threadIdx.x;            // 0..191
    if (blk < MM) {
        int b = blk >> 5;
        int l = blk & 31;
        const int* pb = pos + b * (LL + 1);
        int start = pb[l] + 1;
        int end   = pb[l + 1] + 1;
        if (l == LL - 1) end += 1;          // last clause also takes the SEP
        float inv = 1.0f / (float)(end - start);
        const float* base = seq + (size_t)b * SS * HH;
        float4 a = make_float4(0.f, 0.f, 0.f, 0.f);
        for (int t = start; t < end; ++t) {
            float4 v = reinterpret_cast<const float4*>(base + (size_t)t * HH)[tid];
            a.x += v.x; a.y += v.y; a.z += v.z; a.w += v.w;
        }
        unsigned short* o = Abf + (size_t)blk * DD;
        ushort4 m;
        m.x = f2bf(a.x * inv); m.y = f2bf(a.y * inv);
        m.z = f2bf(a.z * inv); m.w = f2bf(a.w * inv);
        reinterpret_cast<ushort4*>(o)[tid] = m;
        float4 c = reinterpret_cast<const float4*>(base)[tid];   // CLS = token 0
        ushort4 cc;
        cc.x = f2bf(c.x); cc.y = f2bf(c.y); cc.z = f2bf(c.z); cc.w = f2bf(c.w);
        reinterpret_cast<ushort4*>(o + HH)[tid] = cc;
    } else if (blk < MM + 3072) {
        int i = ((blk - MM) * 192 + tid) * 4;        // DD*DD = 3072*192*4
        float4 v = *(const float4*)(Wp + i);
        ushort4 o;
        o.x = f2bf(v.x); o.y = f2bf(v.y); o.z = f2bf(v.z); o.w = f2bf(v.w);
        *(ushort4*)(Wbf + i) = o;
    } else {
        int i = (blk - MM - 3072) * 192 + tid;
        if (i < MM) out[i] = bo[0];
    }
}

// ---------------------------------------------------------------------------
// GEMM with in-block split-K x2: tile 64x64, 8 waves (512 thr). Waves 0-3
// compute K[0,768), waves 4-7 K[768,1536); each group is 2x2 over the tile
// (wave tile 32x32, R5-proven geometry). 12 macro-steps each staging a
// 64x128 A + B slice (4 gloads/wave, m97 ratio). 2 LDS bufs (64 KB) -> 2
// blocks/CU resident = 16 waves/CU = 4/SIMD (vs R5's 3/SIMD). Plain
// __syncthreads (compiler-managed waits, m97-style; R7 proved hand-vmcnt
// buys nothing at this occupancy). XOR swizzle for 256B rows:
// LDS[row][slot] = global chunk slot^(row&15) (source pre-swizzle, rule #21).
// End: ks=1 waves ship acc via LDS (aliasing As), ks=0 waves combine +
// fused tanh(acc+b_pool)*W_out epilogue, 16-lane shfl reduce, atomicAdd.
// XCD chunk: 8bm x 12bn per XCD -> A 1.57 MB + B 2.36 MB < 4 MB L2.
// ---------------------------------------------------------------------------
__global__ __launch_bounds__(512, 4)
void gemm_mfma(const unsigned short* __restrict__ A,   // [MM][KK] bf16
               const unsigned short* __restrict__ Bm,  // [DD][KK] bf16
               const float* __restrict__ bp,           // [DD]
               const float* __restrict__ Wo,           // [DD]
               float* __restrict__ out) {              // [MM]
    __shared__ unsigned short As[2 * 8192];  // 2 bufs x 64x128 bf16 = 32 KB
    __shared__ unsigned short Bs[2 * 8192];  // 32 KB (total 64 KB -> 2 blk/CU)
    const int tid  = threadIdx.x;
    const int wid  = tid >> 6;          // 0..7
    const int lane = tid & 63;
    const int fr   = lane & 15;
    const int fq   = lane >> 4;
    const int ks   = wid >> 2;          // K-group: 0 -> K[0,768), 1 -> K[768,1536)
    const int w2   = wid & 3;
    const int wr   = w2 >> 1, wc = w2 & 1;

    // XCD-aware chunking: xcd = blk&7 (HW round-robin); chunk 8 bm x 12 bn
    const int blk = blockIdx.x;             // 0..767
    const int c = blk & 7;
    const int i = blk >> 3;                 // 0..95
    const int bm = ((c >> 1) << 3) + (i & 7);     // 0..31
    const int bn = (c & 1) * 12 + (i >> 3);       // 0..23
    const int brow = bm * 64;
    const int bcol = bn * 64;

    // staging: wave wid covers rows [wid*8, +8) of the 64x128 slice via 2
    // gloads (each 4 rows: lane l -> row +l>>4, chunk (l&15)^(row&15),
    // source pre-swizzled so the linear LDS dest yields the swizzled image)
    const int l16 = lane >> 4;               // 0..3
    const int c16 = lane & 15;
    const int row0 = wid * 8 + l16;          // gload j adds j*4
    const int row1 = row0 + 4;
    const unsigned short* gA0 = A  + (size_t)(brow + row0) * KK + (c16 ^ (row0 & 15)) * 8;
    const unsigned short* gA1 = A  + (size_t)(brow + row1) * KK + (c16 ^ (row1 & 15)) * 8;
    const unsigned short* gB0 = Bm + (size_t)(bcol + row0) * KK + (c16 ^ (row0 & 15)) * 8;
    const unsigned short* gB1 = Bm + (size_t)(bcol + row1) * KK + (c16 ^ (row1 & 15)) * 8;

#define STAGE(buf, t) do {                                            \
        gload16(gA0 + (t) * 128, &As[(buf) * 8192 + wid * 1024]);     \
        gload16(gA1 + (t) * 128, &As[(buf) * 8192 + wid * 1024 + 512]);\
        gload16(gB0 + (t) * 128, &Bs[(buf) * 8192 + wid * 1024]);     \
        gload16(gB1 + (t) * 128, &Bs[(buf) * 8192 + wid * 1024 + 512]);\
    } while (0)

    // read offsets: frag row = g*16 + fr (row&15 == fr); desired chunk for
    // k-half h of group ks = ks*8 + h*4 + fq; slot = chunk ^ fr
    const int kb = ks * 8;
    int oA[2][2], oB[2][2];                  // [m or n][h]
    #pragma unroll
    for (int m = 0; m < 2; ++m)
        #pragma unroll
        for (int h = 0; h < 2; ++h) {
            oA[m][h] = (wr * 32 + m * 16 + fr) * 128 + ((kb + h * 4 + fq) ^ fr) * 8;
            oB[m][h] = (wc * 32 + m * 16 + fr) * 128 + ((kb + h * 4 + fq) ^ fr) * 8;
        }

    f32x4 acc[2][2] = {};

    STAGE(0, 0);

    #pragma unroll
    for (int t = 0; t < NMS; ++t) {
        const int buf = t & 1;
        __syncthreads();                     // buf[t] ready; prev reads done
        if (t + 1 < NMS) STAGE(buf ^ 1, t + 1);
        const unsigned short* as_ = As + buf * 8192;
        const unsigned short* bs_ = Bs + buf * 8192;
        #pragma unroll
        for (int h = 0; h < 2; ++h) {
            bf16x8 a0 = *(const bf16x8*)(as_ + oA[0][h]);
            bf16x8 a1 = *(const bf16x8*)(as_ + oA[1][h]);
            bf16x8 b0 = *(const bf16x8*)(bs_ + oB[0][h]);
            bf16x8 b1 = *(const bf16x8*)(bs_ + oB[1][h]);
            acc[0][0] = __builtin_amdgcn_mfma_f32_16x16x32_bf16(a0, b0, acc[0][0], 0, 0, 0);
            acc[0][1] = __builtin_amdgcn_mfma_f32_16x16x32_bf16(a0, b1, acc[0][1], 0, 0, 0);
            acc[1][0] = __builtin_amdgcn_mfma_f32_16x16x32_bf16(a1, b0, acc[1][0], 0, 0, 0);
            acc[1][1] = __builtin_amdgcn_mfma_f32_16x16x32_bf16(a1, b1, acc[1][1], 0, 0, 0);
        }
    }
#undef STAGE

    // ---- combine K-groups: ks=1 waves ship acc via LDS (alias As) ----
    __syncthreads();                          // all LDS reads of As/Bs done
    float* xch = (float*)As;                  // 4 w2 x 4 mn x 64 lanes x 4 f32
    if (ks == 1) {
        #pragma unroll
        for (int m = 0; m < 2; ++m)
            #pragma unroll
            for (int n = 0; n < 2; ++n)
                *(f32x4*)&xch[(((w2 * 4 + m * 2 + n) * 64) + lane) * 4] = acc[m][n];
    }
    __syncthreads();
    if (ks == 1) return;

    // ---- ks=0 waves: combine + fused epilogue ----
    // C/D layout: col=lane&15, row=(lane>>4)*4+reg (m89-verified)
    #pragma unroll
    for (int m = 0; m < 2; ++m) {
        float vsum[4] = {0.f, 0.f, 0.f, 0.f};
        #pragma unroll
        for (int n = 0; n < 2; ++n) {
            f32x4 s = acc[m][n] +
                *(const f32x4*)&xch[(((w2 * 4 + m * 2 + n) * 64) + lane) * 4];
            const int col = bcol + wc * 32 + n * 16 + fr;
            const float wo_ = Wo[col];
            const float pb_ = bp[col];
            #pragma unroll
            for (int r = 0; r < 4; ++r) {
                float x = s[r] + pb_;
                float th = 1.f - 2.f / (__expf(2.f * x) + 1.f);  // tanh(x)
                vsum[r] += th * wo_;
            }
        }
        #pragma unroll
        for (int r = 0; r < 4; ++r) {
            float v = vsum[r];
            v += __shfl_xor(v, 1, 16);
            v += __shfl_xor(v, 2, 16);
            v += __shfl_xor(v, 4, 16);
            v += __shfl_xor(v, 8, 16);
            if (fr == 0)
                atomicAdd(&out[brow + wr * 32 + m * 16 + fq * 4 + r], v);
        }
    }
}

// ---------------------------------------------------------------------------
extern "C" void kernel_launch(void* const* d_in, const int* in_sizes, int n_in,
                              void* d_out, int out_size, void* d_ws, size_t ws_size,
                              hipStream_t stream) {
    const float* seq   = (const float*)d_in[0];  // [B,S,H]
    // d_in[1] = context_h (unused by reference)
    const float* Wp    = (const float*)d_in[2];  // [D,D]
    const float* bp    = (const float*)d_in[3];  // [D]
    const float* Wo    = (const float*)d_in[4];  // [D]
    const float* bo    = (const float*)d_in[5];  // scalar
    const int*   pos   = (const int*)d_in[6];    // [B,L+1]
    // d_in[7] = doc_lens (unused by reference)
    float* out = (float*)d_out;                  // [B,L] = 2048

    unsigned short* Abf = (unsigned short*)d_ws;       // [MM][DD] bf16
    unsigned short* Wbf = Abf + (size_t)MM * DD;       // [DD][DD] bf16

    const int ninit = (MM + 191) / 192;                // 11
    prep<<<MM + 3072 + ninit, 192, 0, stream>>>(seq, pos, Wp, bo, Abf, Wbf, out);
    gemm_mfma<<<768, 512, 0, stream>>>(Abf, Wbf, bp, Wo, out);
}